// Round 5
// baseline (719.358 us; speedup 1.0000x reference)
//
#include <hip/hip_runtime.h>

// LGCN encoder. CSR-gather SpMM (16-lane float4, 4 nnz in flight) plus a
// cache-friendly 2-pass CSR build: LDS-staged bucket binning (row>>12) with
// coalesced flushes, then scatter within small per-bucket windows.

constexpr int USER_NUM = 50000;
constexpr int ITEM_NUM = 50000;
constexpr int N_NODES  = USER_NUM + ITEM_NUM;   // 100000
constexpr int EMB      = 64;
constexpr int EMB4     = EMB / 4;               // 16
constexpr int N_LAYERS = 3;
constexpr int TOTAL    = N_NODES * EMB;         // 6,400,000 floats
constexpr int TOTAL4   = TOTAL / 4;
constexpr int U4       = USER_NUM * EMB / 4;

constexpr int RSHIFT = 12;                      // 4096 rows per bucket
constexpr int KA = (N_NODES + 4095) / 4096;     // 25 buckets (adj)
constexpr int KS = (USER_NUM + 4095) / 4096;    // 13 buckets (S)
constexpr int BCHUNK = 2048;                    // entries per binning block

__global__ void init_kernel(const float* __restrict__ user_emb,
                            const float* __restrict__ item_emb,
                            float* __restrict__ ego,
                            float* __restrict__ acc) {
    int i = blockIdx.x * blockDim.x + threadIdx.x;
    if (i >= TOTAL4) return;
    float4 v = (i < U4) ? reinterpret_cast<const float4*>(user_emb)[i]
                        : reinterpret_cast<const float4*>(item_emb)[i - U4];
    reinterpret_cast<float4*>(ego)[i] = v;
    reinterpret_cast<float4*>(acc)[i] = v;
}

__global__ void zero2(int* __restrict__ a, int na, int* __restrict__ b, int nb) {
    int i = blockIdx.x * blockDim.x + threadIdx.x;
    if (i < na) a[i] = 0;
    if (i < nb) b[i] = 0;
}

__global__ void count2(const int* __restrict__ arows, int annz, int* __restrict__ acnt,
                       const int* __restrict__ srows, int snnz, int* __restrict__ scnt) {
    int i = blockIdx.x * blockDim.x + threadIdx.x;
    if (i < annz) atomicAdd(&acnt[arows[i]], 1);
    else if (i - annz < snnz) atomicAdd(&scnt[srows[i - annz]], 1);
}

__global__ void scan_local2(const int* __restrict__ cntA, int* __restrict__ ptrA,
                            int* __restrict__ bsumA, int nA, int nbA,
                            const int* __restrict__ cntS, int* __restrict__ ptrS,
                            int* __restrict__ bsumS, int nS) {
    __shared__ int buf[1024];
    const int* cnt; int* ptr; int* bsum; int n; int b;
    if ((int)blockIdx.x < nbA) { cnt = cntA; ptr = ptrA; bsum = bsumA; n = nA; b = blockIdx.x; }
    else                       { cnt = cntS; ptr = ptrS; bsum = bsumS; n = nS; b = blockIdx.x - nbA; }
    int i = b * 1024 + (int)threadIdx.x;
    int v = (i < n) ? cnt[i] : 0;
    buf[threadIdx.x] = v;
    __syncthreads();
    for (int off = 1; off < 1024; off <<= 1) {
        int t = (threadIdx.x >= (unsigned)off) ? buf[threadIdx.x - off] : 0;
        __syncthreads();
        buf[threadIdx.x] += t;
        __syncthreads();
    }
    if (i < n) ptr[i] = buf[threadIdx.x] - v;
    if (threadIdx.x == 1023) bsum[b] = buf[1023];
}

__global__ void scan_bsums2(int* __restrict__ bsumA, int* __restrict__ ptrA, int nbA, int nA,
                            int* __restrict__ bsumS, int* __restrict__ ptrS, int nbS, int nS) {
    __shared__ int buf[1024];
    int* bsum; int* ptr; int nb; int n;
    if (blockIdx.x == 0) { bsum = bsumA; ptr = ptrA; nb = nbA; n = nA; }
    else                 { bsum = bsumS; ptr = ptrS; nb = nbS; n = nS; }
    int v = ((int)threadIdx.x < nb) ? bsum[threadIdx.x] : 0;
    buf[threadIdx.x] = v;
    __syncthreads();
    for (int off = 1; off < 1024; off <<= 1) {
        int t = (threadIdx.x >= (unsigned)off) ? buf[threadIdx.x - off] : 0;
        __syncthreads();
        buf[threadIdx.x] += t;
        __syncthreads();
    }
    if ((int)threadIdx.x < nb) bsum[threadIdx.x] = buf[threadIdx.x] - v;
    if (threadIdx.x == 1023) ptr[n] = buf[1023];
}

__global__ void add_offsets2(int* __restrict__ ptrA, const int* __restrict__ bsumA,
                             int* __restrict__ workA, int nA,
                             int* __restrict__ ptrS, const int* __restrict__ bsumS,
                             int* __restrict__ workS, int nS) {
    int i = blockIdx.x * blockDim.x + threadIdx.x;
    if (i < nA) { int v = ptrA[i] + bsumA[i >> 10]; ptrA[i] = v; workA[i] = v; }
    if (i < nS) { int v = ptrS[i] + bsumS[i >> 10]; ptrS[i] = v; workS[i] = v; }
}

// aux bucket tails start at the CSR offset of each bucket's first row
__global__ void init_tails(const int* __restrict__ ptrA, int* __restrict__ tailA,
                           const int* __restrict__ ptrS, int* __restrict__ tailS) {
    int t = threadIdx.x;
    if (t < KA) tailA[t] = ptrA[t << RSHIFT];
    if (t < KS) tailS[t] = ptrS[t << RSHIFT];
}

// Pass 1: LDS-staged binning by row>>RSHIFT; coalesced flush of bucket runs.
__global__ void __launch_bounds__(256) bucket_bin(
    const int* __restrict__ arows, const int* __restrict__ acols,
    const float* __restrict__ avals, int annz, int nchA, int* __restrict__ tailA,
    int* __restrict__ auxRA, int* __restrict__ auxCA, float* __restrict__ auxVA,
    const int* __restrict__ srows, const int* __restrict__ scols,
    const float* __restrict__ svals, int snnz, int* __restrict__ tailS,
    int* __restrict__ auxRS, int* __restrict__ auxCS, float* __restrict__ auxVS)
{
    __shared__ int hcnt[32], hoff[32], hcur[32], hbase[32];
    __shared__ int sR[BCHUNK], sC[BCHUNK];
    __shared__ float sV[BCHUNK];
    const int* rows; const int* cols; const float* vals; int nnz; int* tail;
    int* auxR; int* auxC; float* auxV; int chunk;
    if ((int)blockIdx.x < nchA) {
        rows = arows; cols = acols; vals = avals; nnz = annz; tail = tailA;
        auxR = auxRA; auxC = auxCA; auxV = auxVA; chunk = blockIdx.x;
    } else {
        rows = srows; cols = scols; vals = svals; nnz = snnz; tail = tailS;
        auxR = auxRS; auxC = auxCS; auxV = auxVS; chunk = blockIdx.x - nchA;
    }
    int begE = chunk * BCHUNK;
    int cnt = nnz - begE; if (cnt > BCHUNK) cnt = BCHUNK;
    int t = threadIdx.x;
    if (t < 32) hcnt[t] = 0;
    __syncthreads();
    int r[8], c[8]; float v[8];
    for (int k = 0; k < 8; ++k) {
        int idx = t + k * 256;
        if (idx < cnt) {
            int e = begE + idx;
            r[k] = rows[e]; c[k] = cols[e]; v[k] = vals[e];
            atomicAdd(&hcnt[r[k] >> RSHIFT], 1);
        }
    }
    __syncthreads();
    if (t == 0) {
        int run = 0;
        for (int b = 0; b < 32; ++b) { hoff[b] = run; hcur[b] = run; run += hcnt[b]; }
    }
    __syncthreads();
    for (int k = 0; k < 8; ++k) {
        int idx = t + k * 256;
        if (idx < cnt) {
            int b = r[k] >> RSHIFT;
            int pos = atomicAdd(&hcur[b], 1);
            sR[pos] = r[k]; sC[pos] = c[k]; sV[pos] = v[k];
        }
    }
    __syncthreads();
    if (t < 32 && hcnt[t] > 0) hbase[t] = atomicAdd(&tail[t], hcnt[t]);
    __syncthreads();
    for (int idx = t; idx < cnt; idx += 256) {
        int b = sR[idx] >> RSHIFT;
        int g = hbase[b] + (idx - hoff[b]);
        auxR[g] = sR[idx]; auxC[g] = sC[idx]; auxV[g] = sV[idx];
    }
}

// Pass 2: scatter within per-bucket windows (dst range per block ~<512 KB).
__global__ void __launch_bounds__(256) bucket_scatter(
    const int* __restrict__ auxRA, const int* __restrict__ auxCA,
    const float* __restrict__ auxVA, int annz, int nchA,
    int* __restrict__ workA, int2* __restrict__ packA,
    const int* __restrict__ auxRS, const int* __restrict__ auxCS,
    const float* __restrict__ auxVS, int snnz,
    int* __restrict__ workS, int2* __restrict__ packS)
{
    const int* auxR; const int* auxC; const float* auxV;
    int nnz; int* work; int2* pack; int chunk;
    if ((int)blockIdx.x < nchA) {
        auxR = auxRA; auxC = auxCA; auxV = auxVA; nnz = annz;
        work = workA; pack = packA; chunk = blockIdx.x;
    } else {
        auxR = auxRS; auxC = auxCS; auxV = auxVS; nnz = snnz;
        work = workS; pack = packS; chunk = blockIdx.x - nchA;
    }
    int begE = chunk * BCHUNK;
    int endE = begE + BCHUNK; if (endE > nnz) endE = nnz;
    for (int idx = begE + (int)threadIdx.x; idx < endE; idx += 256) {
        int rr = auxR[idx];
        int pos = atomicAdd(&work[rr], 1);
        pack[pos] = make_int2(auxC[idx], __float_as_int(auxV[idx]));
    }
}

__device__ __forceinline__ float4 group_reduce4(float4 a) {
    for (int m = 16; m < 64; m <<= 1) {
        a.x += __shfl_xor(a.x, m, 64);
        a.y += __shfl_xor(a.y, m, 64);
        a.z += __shfl_xor(a.z, m, 64);
        a.w += __shfl_xor(a.w, m, 64);
    }
    return a;
}

__global__ void spmm_s(const int* __restrict__ ptr, const int2* __restrict__ pack,
                       const float* __restrict__ ego, float* __restrict__ hu) {
    int r = blockIdx.x * (blockDim.x >> 6) + (threadIdx.x >> 6);
    if (r >= USER_NUM) return;
    int lane = threadIdx.x & 63;
    int g = lane >> 4, li = lane & 15;
    int beg = ptr[r], end = ptr[r + 1];
    const float4* ego4 = reinterpret_cast<const float4*>(ego);
    float4 acc = make_float4(0.f, 0.f, 0.f, 0.f);
    for (int j = beg + g; j < end; j += 4) {
        int2 p = pack[j];
        float v = __int_as_float(p.y);
        float4 x = ego4[p.x * EMB4 + li];
        acc.x += v * x.x; acc.y += v * x.y; acc.z += v * x.z; acc.w += v * x.w;
    }
    acc = group_reduce4(acc);
    if (g == 0) {
        float4 e = ego4[r * EMB4 + li];
        acc.x += e.x; acc.y += e.y; acc.z += e.z; acc.w += e.w;
        reinterpret_cast<float4*>(hu)[r * EMB4 + li] = acc;
    }
}

__global__ void spmm_adj(const int* __restrict__ ptr, const int2* __restrict__ pack,
                         const float* __restrict__ hu, const float* __restrict__ ego,
                         float* __restrict__ next, float* __restrict__ accbuf, int last) {
    int r = blockIdx.x * (blockDim.x >> 6) + (threadIdx.x >> 6);
    if (r >= N_NODES) return;
    int lane = threadIdx.x & 63;
    int g = lane >> 4, li = lane & 15;
    int beg = ptr[r], end = ptr[r + 1];
    const float4* ego4 = reinterpret_cast<const float4*>(ego);
    const float4* hu4  = reinterpret_cast<const float4*>(hu);
    float4 acc = make_float4(0.f, 0.f, 0.f, 0.f);
    for (int j = beg + g; j < end; j += 4) {
        int2 p = pack[j];
        float v = __int_as_float(p.y);
        float4 x = (p.x < USER_NUM) ? hu4[p.x * EMB4 + li] : ego4[p.x * EMB4 + li];
        acc.x += v * x.x; acc.y += v * x.y; acc.z += v * x.z; acc.w += v * x.w;
    }
    acc = group_reduce4(acc);
    if (g == 0) {
        reinterpret_cast<float4*>(next)[r * EMB4 + li] = acc;
        float4 a = reinterpret_cast<float4*>(accbuf)[r * EMB4 + li];
        a.x += acc.x; a.y += acc.y; a.z += acc.z; a.w += acc.w;
        if (last) { a.x *= 0.25f; a.y *= 0.25f; a.z *= 0.25f; a.w *= 0.25f; }
        reinterpret_cast<float4*>(accbuf)[r * EMB4 + li] = a;
    }
}

extern "C" void kernel_launch(void* const* d_in, const int* in_sizes, int n_in,
                              void* d_out, int out_size, void* d_ws, size_t ws_size,
                              hipStream_t stream) {
    const float* user_emb = (const float*)d_in[0];
    const float* item_emb = (const float*)d_in[1];
    const int*   adj_rows = (const int*)d_in[2];
    const int*   adj_cols = (const int*)d_in[3];
    const float* adj_vals = (const float*)d_in[4];
    const int*   s_rows   = (const int*)d_in[5];
    const int*   s_cols   = (const int*)d_in[6];
    const float* s_vals   = (const float*)d_in[7];
    const int adj_nnz = in_sizes[2];
    const int s_nnz   = in_sizes[5];

    float* acc = (float*)d_out;

    char* p = (char*)d_ws;
    auto alloc = [&](size_t bytes) { void* q = p; p += (bytes + 255) & ~(size_t)255; return q; };
    float* egoA  = (float*)alloc((size_t)TOTAL * 4);
    float* egoB  = (float*)alloc((size_t)TOTAL * 4);   // aliased as adj aux during build
    float* hu    = (float*)alloc((size_t)USER_NUM * EMB * 4);  // aliased as S aux
    int*   ptrA  = (int*)alloc((size_t)(N_NODES + 1) * 4);
    int*   workA = (int*)alloc((size_t)N_NODES * 4);
    int2*  packA = (int2*)alloc((size_t)adj_nnz * 8);
    int*   ptrS  = (int*)alloc((size_t)(USER_NUM + 1) * 4);
    int*   workS = (int*)alloc((size_t)USER_NUM * 4);
    int2*  packS = (int2*)alloc((size_t)s_nnz * 8);
    int*   bsumA = (int*)alloc(1024 * 4);
    int*   bsumS = (int*)alloc(1024 * 4);
    int*   tailA = (int*)alloc(32 * 4);
    int*   tailS = (int*)alloc(32 * 4);

    // aux arrays alias egoB (adj: 3 x 6.4 MB = 19.2 <= 25.6) and hu (S: 9.6 <= 12.8)
    int*   auxRA = (int*)egoB;
    int*   auxCA = auxRA + adj_nnz;
    float* auxVA = (float*)(auxCA + adj_nnz);
    int*   auxRS = (int*)hu;
    int*   auxCS = auxRS + s_nnz;
    float* auxVS = (float*)(auxCS + s_nnz);

    const int BLK = 256;
    const int ew_grid = (TOTAL4 + BLK - 1) / BLK;
    const int nbA = (N_NODES + 1023) / 1024;
    const int nbS = (USER_NUM + 1023) / 1024;
    const int nchA = (adj_nnz + BCHUNK - 1) / BCHUNK;
    const int nchS = (s_nnz + BCHUNK - 1) / BCHUNK;

    // ---- CSR build ----
    zero2<<<(N_NODES + BLK - 1) / BLK, BLK, 0, stream>>>(workA, N_NODES, workS, USER_NUM);
    count2<<<(adj_nnz + s_nnz + BLK - 1) / BLK, BLK, 0, stream>>>(adj_rows, adj_nnz, workA,
                                                                  s_rows, s_nnz, workS);
    scan_local2<<<nbA + nbS, 1024, 0, stream>>>(workA, ptrA, bsumA, N_NODES, nbA,
                                                workS, ptrS, bsumS, USER_NUM);
    scan_bsums2<<<2, 1024, 0, stream>>>(bsumA, ptrA, nbA, N_NODES,
                                        bsumS, ptrS, nbS, USER_NUM);
    add_offsets2<<<(N_NODES + BLK - 1) / BLK, BLK, 0, stream>>>(ptrA, bsumA, workA, N_NODES,
                                                                ptrS, bsumS, workS, USER_NUM);
    init_tails<<<1, 64, 0, stream>>>(ptrA, tailA, ptrS, tailS);
    bucket_bin<<<nchA + nchS, 256, 0, stream>>>(
        adj_rows, adj_cols, adj_vals, adj_nnz, nchA, tailA, auxRA, auxCA, auxVA,
        s_rows, s_cols, s_vals, s_nnz, tailS, auxRS, auxCS, auxVS);
    bucket_scatter<<<nchA + nchS, 256, 0, stream>>>(
        auxRA, auxCA, auxVA, adj_nnz, nchA, workA, packA,
        auxRS, auxCS, auxVS, s_nnz, workS, packS);

    // ---- init ego + acc ----
    init_kernel<<<ew_grid, BLK, 0, stream>>>(user_emb, item_emb, egoA, acc);

    float* ego  = egoA;
    float* next = egoB;
    const int s_grid   = (USER_NUM + 3) / 4;
    const int adj_grid = (N_NODES + 3) / 4;

    for (int l = 0; l < N_LAYERS; ++l) {
        spmm_s<<<s_grid, BLK, 0, stream>>>(ptrS, packS, ego, hu);
        spmm_adj<<<adj_grid, BLK, 0, stream>>>(ptrA, packA, hu, ego, next, acc,
                                               l == N_LAYERS - 1 ? 1 : 0);
        float* t = ego; ego = next; next = t;
    }
}

// Round 6
// 632.206 us; speedup vs baseline: 1.1379x; 1.1379x over previous
//
#include <hip/hip_runtime.h>

// LGCN encoder. CSR-gather SpMM (16-lane float4, 4 nnz in flight).
// CSR build: count/scan, coarse bucket binning (row>>12, coalesced flushes),
// then per-bucket counting-sort scatter: ONE block per bucket with LDS row
// cursors, so each pack cache line is written by a single XCD (no cross-XCD
// partial-line write amplification).

constexpr int USER_NUM = 50000;
constexpr int ITEM_NUM = 50000;
constexpr int N_NODES  = USER_NUM + ITEM_NUM;   // 100000
constexpr int EMB      = 64;
constexpr int EMB4     = EMB / 4;               // 16
constexpr int N_LAYERS = 3;
constexpr int TOTAL    = N_NODES * EMB;         // 6,400,000 floats
constexpr int TOTAL4   = TOTAL / 4;
constexpr int U4       = USER_NUM * EMB / 4;

constexpr int RSHIFT = 12;                      // 4096 rows per bucket
constexpr int RB     = 1 << RSHIFT;
constexpr int KA = (N_NODES + RB - 1) / RB;     // 25 buckets (adj)
constexpr int KS = (USER_NUM + RB - 1) / RB;    // 13 buckets (S)
constexpr int BCHUNK = 2048;                    // entries per binning block

__global__ void init_kernel(const float* __restrict__ user_emb,
                            const float* __restrict__ item_emb,
                            float* __restrict__ ego,
                            float* __restrict__ acc) {
    int i = blockIdx.x * blockDim.x + threadIdx.x;
    if (i >= TOTAL4) return;
    float4 v = (i < U4) ? reinterpret_cast<const float4*>(user_emb)[i]
                        : reinterpret_cast<const float4*>(item_emb)[i - U4];
    reinterpret_cast<float4*>(ego)[i] = v;
    reinterpret_cast<float4*>(acc)[i] = v;
}

__global__ void zero2(int* __restrict__ a, int na, int* __restrict__ b, int nb) {
    int i = blockIdx.x * blockDim.x + threadIdx.x;
    if (i < na) a[i] = 0;
    if (i < nb) b[i] = 0;
}

__global__ void count2(const int* __restrict__ arows, int annz, int* __restrict__ acnt,
                       const int* __restrict__ srows, int snnz, int* __restrict__ scnt) {
    int i = blockIdx.x * blockDim.x + threadIdx.x;
    if (i < annz) atomicAdd(&acnt[arows[i]], 1);
    else if (i - annz < snnz) atomicAdd(&scnt[srows[i - annz]], 1);
}

__global__ void scan_local2(const int* __restrict__ cntA, int* __restrict__ ptrA,
                            int* __restrict__ bsumA, int nA, int nbA,
                            const int* __restrict__ cntS, int* __restrict__ ptrS,
                            int* __restrict__ bsumS, int nS) {
    __shared__ int buf[1024];
    const int* cnt; int* ptr; int* bsum; int n; int b;
    if ((int)blockIdx.x < nbA) { cnt = cntA; ptr = ptrA; bsum = bsumA; n = nA; b = blockIdx.x; }
    else                       { cnt = cntS; ptr = ptrS; bsum = bsumS; n = nS; b = blockIdx.x - nbA; }
    int i = b * 1024 + (int)threadIdx.x;
    int v = (i < n) ? cnt[i] : 0;
    buf[threadIdx.x] = v;
    __syncthreads();
    for (int off = 1; off < 1024; off <<= 1) {
        int t = (threadIdx.x >= (unsigned)off) ? buf[threadIdx.x - off] : 0;
        __syncthreads();
        buf[threadIdx.x] += t;
        __syncthreads();
    }
    if (i < n) ptr[i] = buf[threadIdx.x] - v;
    if (threadIdx.x == 1023) bsum[b] = buf[1023];
}

__global__ void scan_bsums2(int* __restrict__ bsumA, int* __restrict__ ptrA, int nbA, int nA,
                            int* __restrict__ bsumS, int* __restrict__ ptrS, int nbS, int nS) {
    __shared__ int buf[1024];
    int* bsum; int* ptr; int nb; int n;
    if (blockIdx.x == 0) { bsum = bsumA; ptr = ptrA; nb = nbA; n = nA; }
    else                 { bsum = bsumS; ptr = ptrS; nb = nbS; n = nS; }
    int v = ((int)threadIdx.x < nb) ? bsum[threadIdx.x] : 0;
    buf[threadIdx.x] = v;
    __syncthreads();
    for (int off = 1; off < 1024; off <<= 1) {
        int t = (threadIdx.x >= (unsigned)off) ? buf[threadIdx.x - off] : 0;
        __syncthreads();
        buf[threadIdx.x] += t;
        __syncthreads();
    }
    if ((int)threadIdx.x < nb) bsum[threadIdx.x] = buf[threadIdx.x] - v;
    if (threadIdx.x == 1023) ptr[n] = buf[1023];
}

__global__ void add_offsets2(int* __restrict__ ptrA, const int* __restrict__ bsumA, int nA,
                             int* __restrict__ ptrS, const int* __restrict__ bsumS, int nS) {
    int i = blockIdx.x * blockDim.x + threadIdx.x;
    if (i < nA) ptrA[i] += bsumA[i >> 10];
    if (i < nS) ptrS[i] += bsumS[i >> 10];
}

// aux bucket tails start at the CSR offset of each bucket's first row
__global__ void init_tails(const int* __restrict__ ptrA, int* __restrict__ tailA,
                           const int* __restrict__ ptrS, int* __restrict__ tailS) {
    int t = threadIdx.x;
    if (t < KA) tailA[t] = ptrA[t << RSHIFT];
    if (t < KS) tailS[t] = ptrS[t << RSHIFT];
}

// Pass 1: LDS-staged binning by row>>RSHIFT; coalesced flush of bucket runs.
__global__ void __launch_bounds__(256) bucket_bin(
    const int* __restrict__ arows, const int* __restrict__ acols,
    const float* __restrict__ avals, int annz, int nchA, int* __restrict__ tailA,
    int* __restrict__ auxRA, int* __restrict__ auxCA, float* __restrict__ auxVA,
    const int* __restrict__ srows, const int* __restrict__ scols,
    const float* __restrict__ svals, int snnz, int* __restrict__ tailS,
    int* __restrict__ auxRS, int* __restrict__ auxCS, float* __restrict__ auxVS)
{
    __shared__ int hcnt[32], hoff[32], hcur[32], hbase[32];
    __shared__ int sR[BCHUNK], sC[BCHUNK];
    __shared__ float sV[BCHUNK];
    const int* rows; const int* cols; const float* vals; int nnz; int* tail;
    int* auxR; int* auxC; float* auxV; int chunk;
    if ((int)blockIdx.x < nchA) {
        rows = arows; cols = acols; vals = avals; nnz = annz; tail = tailA;
        auxR = auxRA; auxC = auxCA; auxV = auxVA; chunk = blockIdx.x;
    } else {
        rows = srows; cols = scols; vals = svals; nnz = snnz; tail = tailS;
        auxR = auxRS; auxC = auxCS; auxV = auxVS; chunk = blockIdx.x - nchA;
    }
    int begE = chunk * BCHUNK;
    int cnt = nnz - begE; if (cnt > BCHUNK) cnt = BCHUNK;
    int t = threadIdx.x;
    if (t < 32) hcnt[t] = 0;
    __syncthreads();
    int r[8], c[8]; float v[8];
    for (int k = 0; k < 8; ++k) {
        int idx = t + k * 256;
        if (idx < cnt) {
            int e = begE + idx;
            r[k] = rows[e]; c[k] = cols[e]; v[k] = vals[e];
            atomicAdd(&hcnt[r[k] >> RSHIFT], 1);
        }
    }
    __syncthreads();
    if (t == 0) {
        int run = 0;
        for (int b = 0; b < 32; ++b) { hoff[b] = run; hcur[b] = run; run += hcnt[b]; }
    }
    __syncthreads();
    for (int k = 0; k < 8; ++k) {
        int idx = t + k * 256;
        if (idx < cnt) {
            int b = r[k] >> RSHIFT;
            int pos = atomicAdd(&hcur[b], 1);
            sR[pos] = r[k]; sC[pos] = c[k]; sV[pos] = v[k];
        }
    }
    __syncthreads();
    if (t < 32 && hcnt[t] > 0) hbase[t] = atomicAdd(&tail[t], hcnt[t]);
    __syncthreads();
    for (int idx = t; idx < cnt; idx += 256) {
        int b = sR[idx] >> RSHIFT;
        int g = hbase[b] + (idx - hoff[b]);
        auxR[g] = sR[idx]; auxC[g] = sC[idx]; auxV[g] = sV[idx];
    }
}

// Pass 2: per-bucket counting sort. ONE block per bucket; LDS row cursors;
// all pack[] lines of a bucket window are written by this single block.
__global__ void __launch_bounds__(1024) bucket_scatter(
    const int* __restrict__ auxRA, const int* __restrict__ auxCA,
    const float* __restrict__ auxVA, const int* __restrict__ ptrA,
    int2* __restrict__ packA,
    const int* __restrict__ auxRS, const int* __restrict__ auxCS,
    const float* __restrict__ auxVS, const int* __restrict__ ptrS,
    int2* __restrict__ packS)
{
    __shared__ int cur[RB];
    const int* auxR; const int* auxC; const float* auxV; const int* ptr;
    int2* pack; int b; int n;
    if ((int)blockIdx.x < KA) {
        auxR = auxRA; auxC = auxCA; auxV = auxVA; ptr = ptrA; pack = packA;
        b = blockIdx.x; n = N_NODES;
    } else {
        auxR = auxRS; auxC = auxCS; auxV = auxVS; ptr = ptrS; pack = packS;
        b = blockIdx.x - KA; n = USER_NUM;
    }
    int rowbase = b << RSHIFT;
    int nrows = n - rowbase; if (nrows > RB) nrows = RB;
    for (int i = threadIdx.x; i < nrows; i += 1024) cur[i] = ptr[rowbase + i];
    __syncthreads();
    int segb = ptr[rowbase];
    int sege = ptr[rowbase + nrows];
    for (int idx = segb + (int)threadIdx.x; idx < sege; idx += 1024) {
        int r = auxR[idx];
        int pos = atomicAdd(&cur[r - rowbase], 1);
        pack[pos] = make_int2(auxC[idx], __float_as_int(auxV[idx]));
    }
}

__device__ __forceinline__ float4 group_reduce4(float4 a) {
    for (int m = 16; m < 64; m <<= 1) {
        a.x += __shfl_xor(a.x, m, 64);
        a.y += __shfl_xor(a.y, m, 64);
        a.z += __shfl_xor(a.z, m, 64);
        a.w += __shfl_xor(a.w, m, 64);
    }
    return a;
}

__global__ void spmm_s(const int* __restrict__ ptr, const int2* __restrict__ pack,
                       const float* __restrict__ ego, float* __restrict__ hu) {
    int r = blockIdx.x * (blockDim.x >> 6) + (threadIdx.x >> 6);
    if (r >= USER_NUM) return;
    int lane = threadIdx.x & 63;
    int g = lane >> 4, li = lane & 15;
    int beg = ptr[r], end = ptr[r + 1];
    const float4* ego4 = reinterpret_cast<const float4*>(ego);
    float4 acc = make_float4(0.f, 0.f, 0.f, 0.f);
    for (int j = beg + g; j < end; j += 4) {
        int2 p = pack[j];
        float v = __int_as_float(p.y);
        float4 x = ego4[p.x * EMB4 + li];
        acc.x += v * x.x; acc.y += v * x.y; acc.z += v * x.z; acc.w += v * x.w;
    }
    acc = group_reduce4(acc);
    if (g == 0) {
        float4 e = ego4[r * EMB4 + li];
        acc.x += e.x; acc.y += e.y; acc.z += e.z; acc.w += e.w;
        reinterpret_cast<float4*>(hu)[r * EMB4 + li] = acc;
    }
}

__global__ void spmm_adj(const int* __restrict__ ptr, const int2* __restrict__ pack,
                         const float* __restrict__ hu, const float* __restrict__ ego,
                         float* __restrict__ next, float* __restrict__ accbuf, int last) {
    int r = blockIdx.x * (blockDim.x >> 6) + (threadIdx.x >> 6);
    if (r >= N_NODES) return;
    int lane = threadIdx.x & 63;
    int g = lane >> 4, li = lane & 15;
    int beg = ptr[r], end = ptr[r + 1];
    const float4* ego4 = reinterpret_cast<const float4*>(ego);
    const float4* hu4  = reinterpret_cast<const float4*>(hu);
    float4 acc = make_float4(0.f, 0.f, 0.f, 0.f);
    for (int j = beg + g; j < end; j += 4) {
        int2 p = pack[j];
        float v = __int_as_float(p.y);
        float4 x = (p.x < USER_NUM) ? hu4[p.x * EMB4 + li] : ego4[p.x * EMB4 + li];
        acc.x += v * x.x; acc.y += v * x.y; acc.z += v * x.z; acc.w += v * x.w;
    }
    acc = group_reduce4(acc);
    if (g == 0) {
        reinterpret_cast<float4*>(next)[r * EMB4 + li] = acc;
        float4 a = reinterpret_cast<float4*>(accbuf)[r * EMB4 + li];
        a.x += acc.x; a.y += acc.y; a.z += acc.z; a.w += acc.w;
        if (last) { a.x *= 0.25f; a.y *= 0.25f; a.z *= 0.25f; a.w *= 0.25f; }
        reinterpret_cast<float4*>(accbuf)[r * EMB4 + li] = a;
    }
}

extern "C" void kernel_launch(void* const* d_in, const int* in_sizes, int n_in,
                              void* d_out, int out_size, void* d_ws, size_t ws_size,
                              hipStream_t stream) {
    const float* user_emb = (const float*)d_in[0];
    const float* item_emb = (const float*)d_in[1];
    const int*   adj_rows = (const int*)d_in[2];
    const int*   adj_cols = (const int*)d_in[3];
    const float* adj_vals = (const float*)d_in[4];
    const int*   s_rows   = (const int*)d_in[5];
    const int*   s_cols   = (const int*)d_in[6];
    const float* s_vals   = (const float*)d_in[7];
    const int adj_nnz = in_sizes[2];
    const int s_nnz   = in_sizes[5];

    float* acc = (float*)d_out;

    char* p = (char*)d_ws;
    auto alloc = [&](size_t bytes) { void* q = p; p += (bytes + 255) & ~(size_t)255; return q; };
    float* egoA  = (float*)alloc((size_t)TOTAL * 4);
    float* egoB  = (float*)alloc((size_t)TOTAL * 4);   // aliased as adj aux during build
    float* hu    = (float*)alloc((size_t)USER_NUM * EMB * 4);  // aliased as S aux
    int*   ptrA  = (int*)alloc((size_t)(N_NODES + 1) * 4);
    int*   workA = (int*)alloc((size_t)N_NODES * 4);
    int2*  packA = (int2*)alloc((size_t)adj_nnz * 8);
    int*   ptrS  = (int*)alloc((size_t)(USER_NUM + 1) * 4);
    int*   workS = (int*)alloc((size_t)USER_NUM * 4);
    int2*  packS = (int2*)alloc((size_t)s_nnz * 8);
    int*   bsumA = (int*)alloc(1024 * 4);
    int*   bsumS = (int*)alloc(1024 * 4);
    int*   tailA = (int*)alloc(32 * 4);
    int*   tailS = (int*)alloc(32 * 4);

    // aux arrays alias egoB (adj: 3 x 6.4 MB = 19.2 <= 25.6) and hu (S: 9.6 <= 12.8)
    int*   auxRA = (int*)egoB;
    int*   auxCA = auxRA + adj_nnz;
    float* auxVA = (float*)(auxCA + adj_nnz);
    int*   auxRS = (int*)hu;
    int*   auxCS = auxRS + s_nnz;
    float* auxVS = (float*)(auxCS + s_nnz);

    const int BLK = 256;
    const int ew_grid = (TOTAL4 + BLK - 1) / BLK;
    const int nbA = (N_NODES + 1023) / 1024;
    const int nbS = (USER_NUM + 1023) / 1024;
    const int nchA = (adj_nnz + BCHUNK - 1) / BCHUNK;
    const int nchS = (s_nnz + BCHUNK - 1) / BCHUNK;

    // ---- CSR build ----
    zero2<<<(N_NODES + BLK - 1) / BLK, BLK, 0, stream>>>(workA, N_NODES, workS, USER_NUM);
    count2<<<(adj_nnz + s_nnz + BLK - 1) / BLK, BLK, 0, stream>>>(adj_rows, adj_nnz, workA,
                                                                  s_rows, s_nnz, workS);
    scan_local2<<<nbA + nbS, 1024, 0, stream>>>(workA, ptrA, bsumA, N_NODES, nbA,
                                                workS, ptrS, bsumS, USER_NUM);
    scan_bsums2<<<2, 1024, 0, stream>>>(bsumA, ptrA, nbA, N_NODES,
                                        bsumS, ptrS, nbS, USER_NUM);
    add_offsets2<<<(N_NODES + BLK - 1) / BLK, BLK, 0, stream>>>(ptrA, bsumA, N_NODES,
                                                                ptrS, bsumS, USER_NUM);
    init_tails<<<1, 64, 0, stream>>>(ptrA, tailA, ptrS, tailS);
    bucket_bin<<<nchA + nchS, 256, 0, stream>>>(
        adj_rows, adj_cols, adj_vals, adj_nnz, nchA, tailA, auxRA, auxCA, auxVA,
        s_rows, s_cols, s_vals, s_nnz, tailS, auxRS, auxCS, auxVS);
    bucket_scatter<<<KA + KS, 1024, 0, stream>>>(
        auxRA, auxCA, auxVA, ptrA, packA,
        auxRS, auxCS, auxVS, ptrS, packS);

    // ---- init ego + acc ----
    init_kernel<<<ew_grid, BLK, 0, stream>>>(user_emb, item_emb, egoA, acc);

    float* ego  = egoA;
    float* next = egoB;
    const int s_grid   = (USER_NUM + 3) / 4;
    const int adj_grid = (N_NODES + 3) / 4;

    for (int l = 0; l < N_LAYERS; ++l) {
        spmm_s<<<s_grid, BLK, 0, stream>>>(ptrS, packS, ego, hu);
        spmm_adj<<<adj_grid, BLK, 0, stream>>>(ptrA, packA, hu, ego, next, acc,
                                               l == N_LAYERS - 1 ? 1 : 0);
        float* t = ego; ego = next; next = t;
    }
}

// Round 7
// 498.524 us; speedup vs baseline: 1.4430x; 1.2682x over previous
//
#include <hip/hip_runtime.h>

// LGCN encoder. CSR-gather SpMM (16-lane float4, 8 nnz in flight via 2x unroll).
// CSR build with NO O(nnz) global atomics (they write through ~32B/op on gfx950):
//   1. bucket_count: LDS bucket histogram, few global atomics per block
//   2. scan_buckets: tiny scan -> bucket bases (aux base == pack base)
//   3. bucket_bin:   LDS-staged binning by row>>11, coalesced flushes to aux
//   4. bucket_fused: one block per bucket: LDS per-row hist + scan -> ptr[],
//                    then in-bucket scatter with LDS cursors (single-XCD lines)

constexpr int USER_NUM = 50000;
constexpr int ITEM_NUM = 50000;
constexpr int N_NODES  = USER_NUM + ITEM_NUM;   // 100000
constexpr int EMB      = 64;
constexpr int EMB4     = EMB / 4;               // 16
constexpr int N_LAYERS = 3;
constexpr int TOTAL    = N_NODES * EMB;         // 6,400,000 floats
constexpr int TOTAL4   = TOTAL / 4;
constexpr int U4       = USER_NUM * EMB / 4;

constexpr int RSHIFT = 11;                      // 2048 rows per bucket
constexpr int RB     = 1 << RSHIFT;
constexpr int KA = (N_NODES + RB - 1) / RB;     // 49 buckets (adj)
constexpr int KS = (USER_NUM + RB - 1) / RB;    // 25 buckets (S)
constexpr int BCHUNK = 2048;                    // entries per binning block
constexpr int CCH    = 4096;                    // entries per counting block

__global__ void init_kernel(const float* __restrict__ user_emb,
                            const float* __restrict__ item_emb,
                            float* __restrict__ ego,
                            float* __restrict__ acc) {
    int i = blockIdx.x * blockDim.x + threadIdx.x;
    if (i >= TOTAL4) return;
    float4 v = (i < U4) ? reinterpret_cast<const float4*>(user_emb)[i]
                        : reinterpret_cast<const float4*>(item_emb)[i - U4];
    reinterpret_cast<float4*>(ego)[i] = v;
    reinterpret_cast<float4*>(acc)[i] = v;
}

__global__ void zero_small(int* __restrict__ bcntA, int* __restrict__ bcntS) {
    if (threadIdx.x < 64) { bcntA[threadIdx.x] = 0; bcntS[threadIdx.x] = 0; }
}

// LDS bucket histogram; one global atomicAdd per (block, nonempty bucket).
__global__ void __launch_bounds__(256) bucket_count(
    const int* __restrict__ arows, int annz, int nchA, int* __restrict__ bcntA,
    const int* __restrict__ srows, int snnz, int* __restrict__ bcntS)
{
    __shared__ int h[64];
    const int* rows; int nnz; int* bcnt; int chunk;
    if ((int)blockIdx.x < nchA) { rows = arows; nnz = annz; bcnt = bcntA; chunk = blockIdx.x; }
    else                        { rows = srows; nnz = snnz; bcnt = bcntS; chunk = blockIdx.x - nchA; }
    int t = threadIdx.x;
    if (t < 64) h[t] = 0;
    __syncthreads();
    int beg = chunk * CCH;
    int end = beg + CCH; if (end > nnz) end = nnz;
    for (int idx = beg + t; idx < end; idx += 256)
        atomicAdd(&h[rows[idx] >> RSHIFT], 1);
    __syncthreads();
    if (t < 64 && h[t] > 0) atomicAdd(&bcnt[t], h[t]);
}

// Tiny scan of bucket counts -> bases (aux base == pack base), tails, ptr[n].
__global__ void scan_buckets(const int* __restrict__ bcntA, int* __restrict__ bbaseA,
                             int* __restrict__ tailA, int* __restrict__ ptrA,
                             const int* __restrict__ bcntS, int* __restrict__ bbaseS,
                             int* __restrict__ tailS, int* __restrict__ ptrS)
{
    __shared__ int bufA[KA + 1], bufS[KS + 1];
    int t = threadIdx.x;
    if (t < KA) bufA[t] = bcntA[t];
    if (t < KS) bufS[t] = bcntS[t];
    __syncthreads();
    if (t == 0) {
        int run = 0;
        for (int i = 0; i < KA; ++i) { int c = bufA[i]; bufA[i] = run; run += c; }
        bufA[KA] = run;
        run = 0;
        for (int i = 0; i < KS; ++i) { int c = bufS[i]; bufS[i] = run; run += c; }
        bufS[KS] = run;
    }
    __syncthreads();
    if (t <= KA) { bbaseA[t] = bufA[t]; if (t < KA) tailA[t] = bufA[t]; }
    if (t <= KS) { bbaseS[t] = bufS[t]; if (t < KS) tailS[t] = bufS[t]; }
    if (t == 0) { ptrA[N_NODES] = bufA[KA]; ptrS[USER_NUM] = bufS[KS]; }
}

// LDS-staged binning by row>>RSHIFT; coalesced flush of bucket runs to aux.
__global__ void __launch_bounds__(256) bucket_bin(
    const int* __restrict__ arows, const int* __restrict__ acols,
    const float* __restrict__ avals, int annz, int nchA, int* __restrict__ tailA,
    int* __restrict__ auxRA, int* __restrict__ auxCA, float* __restrict__ auxVA,
    const int* __restrict__ srows, const int* __restrict__ scols,
    const float* __restrict__ svals, int snnz, int* __restrict__ tailS,
    int* __restrict__ auxRS, int* __restrict__ auxCS, float* __restrict__ auxVS)
{
    __shared__ int hcnt[64], hoff[64], hcur[64], hbase[64];
    __shared__ int sR[BCHUNK], sC[BCHUNK];
    __shared__ float sV[BCHUNK];
    const int* rows; const int* cols; const float* vals; int nnz; int* tail;
    int* auxR; int* auxC; float* auxV; int chunk;
    if ((int)blockIdx.x < nchA) {
        rows = arows; cols = acols; vals = avals; nnz = annz; tail = tailA;
        auxR = auxRA; auxC = auxCA; auxV = auxVA; chunk = blockIdx.x;
    } else {
        rows = srows; cols = scols; vals = svals; nnz = snnz; tail = tailS;
        auxR = auxRS; auxC = auxCS; auxV = auxVS; chunk = blockIdx.x - nchA;
    }
    int begE = chunk * BCHUNK;
    int cnt = nnz - begE; if (cnt > BCHUNK) cnt = BCHUNK;
    int t = threadIdx.x;
    if (t < 64) hcnt[t] = 0;
    __syncthreads();
    int r[8], c[8]; float v[8];
    for (int k = 0; k < 8; ++k) {
        int idx = t + k * 256;
        if (idx < cnt) {
            int e = begE + idx;
            r[k] = rows[e]; c[k] = cols[e]; v[k] = vals[e];
            atomicAdd(&hcnt[r[k] >> RSHIFT], 1);
        }
    }
    __syncthreads();
    if (t == 0) {
        int run = 0;
        for (int b = 0; b < 64; ++b) { hoff[b] = run; hcur[b] = run; run += hcnt[b]; }
    }
    __syncthreads();
    for (int k = 0; k < 8; ++k) {
        int idx = t + k * 256;
        if (idx < cnt) {
            int b = r[k] >> RSHIFT;
            int pos = atomicAdd(&hcur[b], 1);
            sR[pos] = r[k]; sC[pos] = c[k]; sV[pos] = v[k];
        }
    }
    __syncthreads();
    if (t < 64 && hcnt[t] > 0) hbase[t] = atomicAdd(&tail[t], hcnt[t]);
    __syncthreads();
    for (int idx = t; idx < cnt; idx += 256) {
        int b = sR[idx] >> RSHIFT;
        int g = hbase[b] + (idx - hoff[b]);
        auxR[g] = sR[idx]; auxC[g] = sC[idx]; auxV[g] = sV[idx];
    }
}

// One block per bucket: per-row LDS histogram, LDS scan (writes ptr[]),
// then counting-sort scatter into this bucket's private pack window.
__global__ void __launch_bounds__(1024) bucket_fused(
    const int* __restrict__ auxRA, const int* __restrict__ auxCA,
    const float* __restrict__ auxVA, const int* __restrict__ bbaseA,
    int* __restrict__ ptrA, int2* __restrict__ packA,
    const int* __restrict__ auxRS, const int* __restrict__ auxCS,
    const float* __restrict__ auxVS, const int* __restrict__ bbaseS,
    int* __restrict__ ptrS, int2* __restrict__ packS)
{
    __shared__ int cur[RB];
    __shared__ int s1[1024];
    const int* auxR; const int* auxC; const float* auxV; const int* bbase;
    int* ptr; int2* pack; int b; int n;
    if ((int)blockIdx.x < KA) {
        auxR = auxRA; auxC = auxCA; auxV = auxVA; bbase = bbaseA;
        ptr = ptrA; pack = packA; b = blockIdx.x; n = N_NODES;
    } else {
        auxR = auxRS; auxC = auxCS; auxV = auxVS; bbase = bbaseS;
        ptr = ptrS; pack = packS; b = blockIdx.x - KA; n = USER_NUM;
    }
    int rowbase = b << RSHIFT;
    int nrows = n - rowbase; if (nrows > RB) nrows = RB;
    int segb = bbase[b], sege = bbase[b + 1];
    int t = threadIdx.x;
    cur[t] = 0; cur[t + 1024] = 0;
    __syncthreads();
    for (int idx = segb + t; idx < sege; idx += 1024)
        atomicAdd(&cur[auxR[idx] - rowbase], 1);
    __syncthreads();
    int a0 = cur[2 * t], a1 = cur[2 * t + 1];
    s1[t] = a0 + a1;
    __syncthreads();
    for (int off = 1; off < 1024; off <<= 1) {
        int v = (t >= off) ? s1[t - off] : 0;
        __syncthreads();
        s1[t] += v;
        __syncthreads();
    }
    int excl = s1[t] - (a0 + a1);
    int c0 = segb + excl, c1 = segb + excl + a0;
    cur[2 * t] = c0; cur[2 * t + 1] = c1;
    if (2 * t < nrows)     ptr[rowbase + 2 * t] = c0;
    if (2 * t + 1 < nrows) ptr[rowbase + 2 * t + 1] = c1;
    __syncthreads();
    for (int idx = segb + t; idx < sege; idx += 1024) {
        int r = auxR[idx];
        int pos = atomicAdd(&cur[r - rowbase], 1);
        pack[pos] = make_int2(auxC[idx], __float_as_int(auxV[idx]));
    }
}

__device__ __forceinline__ float4 group_reduce4(float4 a) {
    for (int m = 16; m < 64; m <<= 1) {
        a.x += __shfl_xor(a.x, m, 64);
        a.y += __shfl_xor(a.y, m, 64);
        a.z += __shfl_xor(a.z, m, 64);
        a.w += __shfl_xor(a.w, m, 64);
    }
    return a;
}

__global__ void spmm_s(const int* __restrict__ ptr, const int2* __restrict__ pack,
                       const float* __restrict__ ego, float* __restrict__ hu) {
    int r = blockIdx.x * (blockDim.x >> 6) + (threadIdx.x >> 6);
    if (r >= USER_NUM) return;
    int lane = threadIdx.x & 63;
    int g = lane >> 4, li = lane & 15;
    int beg = ptr[r], end = ptr[r + 1];
    const float4* ego4 = reinterpret_cast<const float4*>(ego);
    float4 acc = make_float4(0.f, 0.f, 0.f, 0.f);
    int j = beg + g;
    for (; j + 4 < end; j += 8) {
        int2 p0 = pack[j];
        int2 p1 = pack[j + 4];
        float4 x0 = ego4[p0.x * EMB4 + li];
        float4 x1 = ego4[p1.x * EMB4 + li];
        float v0 = __int_as_float(p0.y), v1 = __int_as_float(p1.y);
        acc.x += v0 * x0.x; acc.y += v0 * x0.y; acc.z += v0 * x0.z; acc.w += v0 * x0.w;
        acc.x += v1 * x1.x; acc.y += v1 * x1.y; acc.z += v1 * x1.z; acc.w += v1 * x1.w;
    }
    if (j < end) {
        int2 p = pack[j];
        float v = __int_as_float(p.y);
        float4 x = ego4[p.x * EMB4 + li];
        acc.x += v * x.x; acc.y += v * x.y; acc.z += v * x.z; acc.w += v * x.w;
    }
    acc = group_reduce4(acc);
    if (g == 0) {
        float4 e = ego4[r * EMB4 + li];
        acc.x += e.x; acc.y += e.y; acc.z += e.z; acc.w += e.w;
        reinterpret_cast<float4*>(hu)[r * EMB4 + li] = acc;
    }
}

__global__ void spmm_adj(const int* __restrict__ ptr, const int2* __restrict__ pack,
                         const float* __restrict__ hu, const float* __restrict__ ego,
                         float* __restrict__ next, float* __restrict__ accbuf, int last) {
    int r = blockIdx.x * (blockDim.x >> 6) + (threadIdx.x >> 6);
    if (r >= N_NODES) return;
    int lane = threadIdx.x & 63;
    int g = lane >> 4, li = lane & 15;
    int beg = ptr[r], end = ptr[r + 1];
    const float4* ego4 = reinterpret_cast<const float4*>(ego);
    const float4* hu4  = reinterpret_cast<const float4*>(hu);
    float4 acc = make_float4(0.f, 0.f, 0.f, 0.f);
    int j = beg + g;
    for (; j + 4 < end; j += 8) {
        int2 p0 = pack[j];
        int2 p1 = pack[j + 4];
        float4 x0 = (p0.x < USER_NUM) ? hu4[p0.x * EMB4 + li] : ego4[p0.x * EMB4 + li];
        float4 x1 = (p1.x < USER_NUM) ? hu4[p1.x * EMB4 + li] : ego4[p1.x * EMB4 + li];
        float v0 = __int_as_float(p0.y), v1 = __int_as_float(p1.y);
        acc.x += v0 * x0.x; acc.y += v0 * x0.y; acc.z += v0 * x0.z; acc.w += v0 * x0.w;
        acc.x += v1 * x1.x; acc.y += v1 * x1.y; acc.z += v1 * x1.z; acc.w += v1 * x1.w;
    }
    if (j < end) {
        int2 p = pack[j];
        float v = __int_as_float(p.y);
        float4 x = (p.x < USER_NUM) ? hu4[p.x * EMB4 + li] : ego4[p.x * EMB4 + li];
        acc.x += v * x.x; acc.y += v * x.y; acc.z += v * x.z; acc.w += v * x.w;
    }
    acc = group_reduce4(acc);
    if (g == 0) {
        reinterpret_cast<float4*>(next)[r * EMB4 + li] = acc;
        float4 a = reinterpret_cast<float4*>(accbuf)[r * EMB4 + li];
        a.x += acc.x; a.y += acc.y; a.z += acc.z; a.w += acc.w;
        if (last) { a.x *= 0.25f; a.y *= 0.25f; a.z *= 0.25f; a.w *= 0.25f; }
        reinterpret_cast<float4*>(accbuf)[r * EMB4 + li] = a;
    }
}

extern "C" void kernel_launch(void* const* d_in, const int* in_sizes, int n_in,
                              void* d_out, int out_size, void* d_ws, size_t ws_size,
                              hipStream_t stream) {
    const float* user_emb = (const float*)d_in[0];
    const float* item_emb = (const float*)d_in[1];
    const int*   adj_rows = (const int*)d_in[2];
    const int*   adj_cols = (const int*)d_in[3];
    const float* adj_vals = (const float*)d_in[4];
    const int*   s_rows   = (const int*)d_in[5];
    const int*   s_cols   = (const int*)d_in[6];
    const float* s_vals   = (const float*)d_in[7];
    const int adj_nnz = in_sizes[2];
    const int s_nnz   = in_sizes[5];

    float* acc = (float*)d_out;

    char* p = (char*)d_ws;
    auto alloc = [&](size_t bytes) { void* q = p; p += (bytes + 255) & ~(size_t)255; return q; };
    float* egoA  = (float*)alloc((size_t)TOTAL * 4);
    float* egoB  = (float*)alloc((size_t)TOTAL * 4);          // aliased as adj aux
    float* hu    = (float*)alloc((size_t)USER_NUM * EMB * 4); // aliased as S aux
    int*   ptrA  = (int*)alloc((size_t)(N_NODES + 1) * 4);
    int2*  packA = (int2*)alloc((size_t)adj_nnz * 8);
    int*   ptrS  = (int*)alloc((size_t)(USER_NUM + 1) * 4);
    int2*  packS = (int2*)alloc((size_t)s_nnz * 8);
    int*   bcntA = (int*)alloc(64 * 4);
    int*   bcntS = (int*)alloc(64 * 4);
    int*   bbaseA= (int*)alloc(64 * 4);
    int*   bbaseS= (int*)alloc(64 * 4);
    int*   tailA = (int*)alloc(64 * 4);
    int*   tailS = (int*)alloc(64 * 4);

    int*   auxRA = (int*)egoB;
    int*   auxCA = auxRA + adj_nnz;
    float* auxVA = (float*)(auxCA + adj_nnz);
    int*   auxRS = (int*)hu;
    int*   auxCS = auxRS + s_nnz;
    float* auxVS = (float*)(auxCS + s_nnz);

    const int BLK = 256;
    const int ew_grid = (TOTAL4 + BLK - 1) / BLK;
    const int nchA = (adj_nnz + BCHUNK - 1) / BCHUNK;
    const int nchS = (s_nnz + BCHUNK - 1) / BCHUNK;
    const int nccA = (adj_nnz + CCH - 1) / CCH;
    const int nccS = (s_nnz + CCH - 1) / CCH;

    // ---- CSR build (no O(nnz) global atomics) ----
    zero_small<<<1, 64, 0, stream>>>(bcntA, bcntS);
    bucket_count<<<nccA + nccS, 256, 0, stream>>>(adj_rows, adj_nnz, nccA, bcntA,
                                                  s_rows, s_nnz, bcntS);
    scan_buckets<<<1, 64, 0, stream>>>(bcntA, bbaseA, tailA, ptrA,
                                       bcntS, bbaseS, tailS, ptrS);
    bucket_bin<<<nchA + nchS, 256, 0, stream>>>(
        adj_rows, adj_cols, adj_vals, adj_nnz, nchA, tailA, auxRA, auxCA, auxVA,
        s_rows, s_cols, s_vals, s_nnz, tailS, auxRS, auxCS, auxVS);
    bucket_fused<<<KA + KS, 1024, 0, stream>>>(
        auxRA, auxCA, auxVA, bbaseA, ptrA, packA,
        auxRS, auxCS, auxVS, bbaseS, ptrS, packS);

    // ---- init ego + acc ----
    init_kernel<<<ew_grid, BLK, 0, stream>>>(user_emb, item_emb, egoA, acc);

    float* ego  = egoA;
    float* next = egoB;
    const int s_grid   = (USER_NUM + 3) / 4;
    const int adj_grid = (N_NODES + 3) / 4;

    for (int l = 0; l < N_LAYERS; ++l) {
        spmm_s<<<s_grid, BLK, 0, stream>>>(ptrS, packS, ego, hu);
        spmm_adj<<<adj_grid, BLK, 0, stream>>>(ptrA, packA, hu, ego, next, acc,
                                               l == N_LAYERS - 1 ? 1 : 0);
        float* t = ego; ego = next; next = t;
    }
}

// Round 8
// 405.983 us; speedup vs baseline: 1.7719x; 1.2279x over previous
//
#include <hip/hip_runtime.h>

// LGCN encoder. bf16 propagated embeddings (halve gather bytes), fp32 acc.
// SpMM: one wave per row, 8 lanes x 16B (uint4 = 8 bf16) per gather, 8 nnz in
// flight (16 with 2x unroll). CSR build: bucket histogram -> tiny scan ->
// LDS-staged binning -> per-bucket counting sort (no O(nnz) global atomics).

constexpr int USER_NUM = 50000;
constexpr int ITEM_NUM = 50000;
constexpr int N_NODES  = USER_NUM + ITEM_NUM;   // 100000
constexpr int EMB      = 64;
constexpr int N_LAYERS = 3;
constexpr int TOTAL    = N_NODES * EMB;         // 6,400,000
constexpr int TOTAL4   = TOTAL / 4;
constexpr int U4       = USER_NUM * EMB / 4;

constexpr int RSHIFT = 11;                      // 2048 rows per bucket
constexpr int RB     = 1 << RSHIFT;
constexpr int KA = (N_NODES + RB - 1) / RB;     // 49
constexpr int KS = (USER_NUM + RB - 1) / RB;    // 25
constexpr int BCHUNK = 2048;
constexpr int CCH    = 4096;

__device__ __forceinline__ unsigned f2bf(float f) {
    unsigned b = __float_as_uint(f);
    return (b + 0x7fffu + ((b >> 16) & 1u)) >> 16;   // RNE
}
__device__ __forceinline__ void bf2x(unsigned u, float& a, float& b) {
    a = __uint_as_float(u << 16);
    b = __uint_as_float(u & 0xffff0000u);
}

// ego (bf16) = concat inputs; acc (fp32, d_out) = same
__global__ void init_kernel(const float* __restrict__ user_emb,
                            const float* __restrict__ item_emb,
                            unsigned* __restrict__ ego2,   // uint = 2 bf16
                            float* __restrict__ acc) {
    int i = blockIdx.x * blockDim.x + threadIdx.x;
    if (i >= TOTAL4) return;
    float4 v = (i < U4) ? reinterpret_cast<const float4*>(user_emb)[i]
                        : reinterpret_cast<const float4*>(item_emb)[i - U4];
    reinterpret_cast<float4*>(acc)[i] = v;
    uint2 o;
    o.x = f2bf(v.x) | (f2bf(v.y) << 16);
    o.y = f2bf(v.z) | (f2bf(v.w) << 16);
    reinterpret_cast<uint2*>(ego2)[i] = o;
}

__global__ void zero_small(int* __restrict__ bcntA, int* __restrict__ bcntS) {
    if (threadIdx.x < 64) { bcntA[threadIdx.x] = 0; bcntS[threadIdx.x] = 0; }
}

__global__ void __launch_bounds__(256) bucket_count(
    const int* __restrict__ arows, int annz, int nchA, int* __restrict__ bcntA,
    const int* __restrict__ srows, int snnz, int* __restrict__ bcntS)
{
    __shared__ int h[64];
    const int* rows; int nnz; int* bcnt; int chunk;
    if ((int)blockIdx.x < nchA) { rows = arows; nnz = annz; bcnt = bcntA; chunk = blockIdx.x; }
    else                        { rows = srows; nnz = snnz; bcnt = bcntS; chunk = blockIdx.x - nchA; }
    int t = threadIdx.x;
    if (t < 64) h[t] = 0;
    __syncthreads();
    int beg = chunk * CCH;
    int end = beg + CCH; if (end > nnz) end = nnz;
    for (int idx = beg + t; idx < end; idx += 256)
        atomicAdd(&h[rows[idx] >> RSHIFT], 1);
    __syncthreads();
    if (t < 64 && h[t] > 0) atomicAdd(&bcnt[t], h[t]);
}

__global__ void scan_buckets(const int* __restrict__ bcntA, int* __restrict__ bbaseA,
                             int* __restrict__ tailA, int* __restrict__ ptrA,
                             const int* __restrict__ bcntS, int* __restrict__ bbaseS,
                             int* __restrict__ tailS, int* __restrict__ ptrS)
{
    __shared__ int bufA[KA + 1], bufS[KS + 1];
    int t = threadIdx.x;
    if (t < KA) bufA[t] = bcntA[t];
    if (t < KS) bufS[t] = bcntS[t];
    __syncthreads();
    if (t == 0) {
        int run = 0;
        for (int i = 0; i < KA; ++i) { int c = bufA[i]; bufA[i] = run; run += c; }
        bufA[KA] = run;
        run = 0;
        for (int i = 0; i < KS; ++i) { int c = bufS[i]; bufS[i] = run; run += c; }
        bufS[KS] = run;
    }
    __syncthreads();
    if (t <= KA) { bbaseA[t] = bufA[t]; if (t < KA) tailA[t] = bufA[t]; }
    if (t <= KS) { bbaseS[t] = bufS[t]; if (t < KS) tailS[t] = bufS[t]; }
    if (t == 0) { ptrA[N_NODES] = bufA[KA]; ptrS[USER_NUM] = bufS[KS]; }
}

__global__ void __launch_bounds__(256) bucket_bin(
    const int* __restrict__ arows, const int* __restrict__ acols,
    const float* __restrict__ avals, int annz, int nchA, int* __restrict__ tailA,
    int* __restrict__ auxRA, int* __restrict__ auxCA, float* __restrict__ auxVA,
    const int* __restrict__ srows, const int* __restrict__ scols,
    const float* __restrict__ svals, int snnz, int* __restrict__ tailS,
    int* __restrict__ auxRS, int* __restrict__ auxCS, float* __restrict__ auxVS)
{
    __shared__ int hcnt[64], hoff[64], hcur[64], hbase[64];
    __shared__ int sR[BCHUNK], sC[BCHUNK];
    __shared__ float sV[BCHUNK];
    const int* rows; const int* cols; const float* vals; int nnz; int* tail;
    int* auxR; int* auxC; float* auxV; int chunk;
    if ((int)blockIdx.x < nchA) {
        rows = arows; cols = acols; vals = avals; nnz = annz; tail = tailA;
        auxR = auxRA; auxC = auxCA; auxV = auxVA; chunk = blockIdx.x;
    } else {
        rows = srows; cols = scols; vals = svals; nnz = snnz; tail = tailS;
        auxR = auxRS; auxC = auxCS; auxV = auxVS; chunk = blockIdx.x - nchA;
    }
    int begE = chunk * BCHUNK;
    int cnt = nnz - begE; if (cnt > BCHUNK) cnt = BCHUNK;
    int t = threadIdx.x;
    if (t < 64) hcnt[t] = 0;
    __syncthreads();
    int r[8], c[8]; float v[8];
    for (int k = 0; k < 8; ++k) {
        int idx = t + k * 256;
        if (idx < cnt) {
            int e = begE + idx;
            r[k] = rows[e]; c[k] = cols[e]; v[k] = vals[e];
            atomicAdd(&hcnt[r[k] >> RSHIFT], 1);
        }
    }
    __syncthreads();
    if (t == 0) {
        int run = 0;
        for (int b = 0; b < 64; ++b) { hoff[b] = run; hcur[b] = run; run += hcnt[b]; }
    }
    __syncthreads();
    for (int k = 0; k < 8; ++k) {
        int idx = t + k * 256;
        if (idx < cnt) {
            int b = r[k] >> RSHIFT;
            int pos = atomicAdd(&hcur[b], 1);
            sR[pos] = r[k]; sC[pos] = c[k]; sV[pos] = v[k];
        }
    }
    __syncthreads();
    if (t < 64 && hcnt[t] > 0) hbase[t] = atomicAdd(&tail[t], hcnt[t]);
    __syncthreads();
    for (int idx = t; idx < cnt; idx += 256) {
        int b = sR[idx] >> RSHIFT;
        int g = hbase[b] + (idx - hoff[b]);
        auxR[g] = sR[idx]; auxC[g] = sC[idx]; auxV[g] = sV[idx];
    }
}

__global__ void __launch_bounds__(1024) bucket_fused(
    const int* __restrict__ auxRA, const int* __restrict__ auxCA,
    const float* __restrict__ auxVA, const int* __restrict__ bbaseA,
    int* __restrict__ ptrA, int2* __restrict__ packA,
    const int* __restrict__ auxRS, const int* __restrict__ auxCS,
    const float* __restrict__ auxVS, const int* __restrict__ bbaseS,
    int* __restrict__ ptrS, int2* __restrict__ packS)
{
    __shared__ int cur[RB];
    __shared__ int s1[1024];
    const int* auxR; const int* auxC; const float* auxV; const int* bbase;
    int* ptr; int2* pack; int b; int n;
    if ((int)blockIdx.x < KA) {
        auxR = auxRA; auxC = auxCA; auxV = auxVA; bbase = bbaseA;
        ptr = ptrA; pack = packA; b = blockIdx.x; n = N_NODES;
    } else {
        auxR = auxRS; auxC = auxCS; auxV = auxVS; bbase = bbaseS;
        ptr = ptrS; pack = packS; b = blockIdx.x - KA; n = USER_NUM;
    }
    int rowbase = b << RSHIFT;
    int nrows = n - rowbase; if (nrows > RB) nrows = RB;
    int segb = bbase[b], sege = bbase[b + 1];
    int t = threadIdx.x;
    cur[t] = 0; cur[t + 1024] = 0;
    __syncthreads();
    for (int idx = segb + t; idx < sege; idx += 1024)
        atomicAdd(&cur[auxR[idx] - rowbase], 1);
    __syncthreads();
    int a0 = cur[2 * t], a1 = cur[2 * t + 1];
    s1[t] = a0 + a1;
    __syncthreads();
    for (int off = 1; off < 1024; off <<= 1) {
        int v = (t >= off) ? s1[t - off] : 0;
        __syncthreads();
        s1[t] += v;
        __syncthreads();
    }
    int excl = s1[t] - (a0 + a1);
    int c0 = segb + excl, c1 = segb + excl + a0;
    cur[2 * t] = c0; cur[2 * t + 1] = c1;
    if (2 * t < nrows)     ptr[rowbase + 2 * t] = c0;
    if (2 * t + 1 < nrows) ptr[rowbase + 2 * t + 1] = c1;
    __syncthreads();
    for (int idx = segb + t; idx < sege; idx += 1024) {
        int r = auxR[idx];
        int pos = atomicAdd(&cur[r - rowbase], 1);
        pack[pos] = make_int2(auxC[idx], __float_as_int(auxV[idx]));
    }
}

__device__ __forceinline__ void gacc(float (&acc)[8], float v, uint4 u) {
    float f0, f1, f2, f3, f4, f5, f6, f7;
    bf2x(u.x, f0, f1); bf2x(u.y, f2, f3); bf2x(u.z, f4, f5); bf2x(u.w, f6, f7);
    acc[0] += v * f0; acc[1] += v * f1; acc[2] += v * f2; acc[3] += v * f3;
    acc[4] += v * f4; acc[5] += v * f5; acc[6] += v * f6; acc[7] += v * f7;
}
__device__ __forceinline__ void reduce8(float (&acc)[8]) {
    for (int m = 8; m < 64; m <<= 1)
        for (int k = 0; k < 8; ++k)
            acc[k] += __shfl_xor(acc[k], m, 64);
}
__device__ __forceinline__ uint4 pack8(const float (&acc)[8]) {
    uint4 o;
    o.x = f2bf(acc[0]) | (f2bf(acc[1]) << 16);
    o.y = f2bf(acc[2]) | (f2bf(acc[3]) << 16);
    o.z = f2bf(acc[4]) | (f2bf(acc[5]) << 16);
    o.w = f2bf(acc[6]) | (f2bf(acc[7]) << 16);
    return o;
}

// hu[r,:] = ego[r,:] + S*ego  (bf16 rows = 8 x uint4; 8 nnz in flight x2)
__global__ void spmm_s(const int* __restrict__ ptr, const int2* __restrict__ pack,
                       const uint4* __restrict__ ego8, uint4* __restrict__ hu8) {
    int r = blockIdx.x * (blockDim.x >> 6) + (threadIdx.x >> 6);
    if (r >= USER_NUM) return;
    int lane = threadIdx.x & 63;
    int g = lane >> 3, li = lane & 7;
    int beg = ptr[r], end = ptr[r + 1];
    float acc[8] = {0, 0, 0, 0, 0, 0, 0, 0};
    int j = beg + g;
    for (; j + 8 < end; j += 16) {
        int2 p0 = pack[j];
        int2 p1 = pack[j + 8];
        uint4 x0 = ego8[p0.x * 8 + li];
        uint4 x1 = ego8[p1.x * 8 + li];
        gacc(acc, __int_as_float(p0.y), x0);
        gacc(acc, __int_as_float(p1.y), x1);
    }
    if (j < end) {
        int2 p = pack[j];
        gacc(acc, __int_as_float(p.y), ego8[p.x * 8 + li]);
    }
    reduce8(acc);
    if (g == 0) {
        uint4 e = ego8[r * 8 + li];
        float f0, f1;
        bf2x(e.x, f0, f1); acc[0] += f0; acc[1] += f1;
        bf2x(e.y, f0, f1); acc[2] += f0; acc[3] += f1;
        bf2x(e.z, f0, f1); acc[4] += f0; acc[5] += f1;
        bf2x(e.w, f0, f1); acc[6] += f0; acc[7] += f1;
        hu8[r * 8 + li] = pack8(acc);
    }
}

// next = A*h (h = hu for user cols, ego for item cols); acc += fp32 result;
// last layer: acc = (acc+result)*0.25 and skip next-store.
__global__ void spmm_adj(const int* __restrict__ ptr, const int2* __restrict__ pack,
                         const uint4* __restrict__ hu8, const uint4* __restrict__ ego8,
                         uint4* __restrict__ next8, float* __restrict__ accbuf, int last) {
    int r = blockIdx.x * (blockDim.x >> 6) + (threadIdx.x >> 6);
    if (r >= N_NODES) return;
    int lane = threadIdx.x & 63;
    int g = lane >> 3, li = lane & 7;
    int beg = ptr[r], end = ptr[r + 1];
    float acc[8] = {0, 0, 0, 0, 0, 0, 0, 0};
    int j = beg + g;
    for (; j + 8 < end; j += 16) {
        int2 p0 = pack[j];
        int2 p1 = pack[j + 8];
        uint4 x0 = (p0.x < USER_NUM) ? hu8[p0.x * 8 + li] : ego8[p0.x * 8 + li];
        uint4 x1 = (p1.x < USER_NUM) ? hu8[p1.x * 8 + li] : ego8[p1.x * 8 + li];
        gacc(acc, __int_as_float(p0.y), x0);
        gacc(acc, __int_as_float(p1.y), x1);
    }
    if (j < end) {
        int2 p = pack[j];
        uint4 x = (p.x < USER_NUM) ? hu8[p.x * 8 + li] : ego8[p.x * 8 + li];
        gacc(acc, __int_as_float(p.y), x);
    }
    reduce8(acc);
    if (g == 0) {
        if (!last) next8[r * 8 + li] = pack8(acc);
        float4* acc4 = reinterpret_cast<float4*>(accbuf);
        int base = r * 16 + li * 2;
        float4 a0 = acc4[base], a1 = acc4[base + 1];
        a0.x += acc[0]; a0.y += acc[1]; a0.z += acc[2]; a0.w += acc[3];
        a1.x += acc[4]; a1.y += acc[5]; a1.z += acc[6]; a1.w += acc[7];
        if (last) {
            a0.x *= 0.25f; a0.y *= 0.25f; a0.z *= 0.25f; a0.w *= 0.25f;
            a1.x *= 0.25f; a1.y *= 0.25f; a1.z *= 0.25f; a1.w *= 0.25f;
        }
        acc4[base] = a0; acc4[base + 1] = a1;
    }
}

extern "C" void kernel_launch(void* const* d_in, const int* in_sizes, int n_in,
                              void* d_out, int out_size, void* d_ws, size_t ws_size,
                              hipStream_t stream) {
    const float* user_emb = (const float*)d_in[0];
    const float* item_emb = (const float*)d_in[1];
    const int*   adj_rows = (const int*)d_in[2];
    const int*   adj_cols = (const int*)d_in[3];
    const float* adj_vals = (const float*)d_in[4];
    const int*   s_rows   = (const int*)d_in[5];
    const int*   s_cols   = (const int*)d_in[6];
    const float* s_vals   = (const float*)d_in[7];
    const int adj_nnz = in_sizes[2];
    const int s_nnz   = in_sizes[5];

    float* acc = (float*)d_out;

    char* p = (char*)d_ws;
    auto alloc = [&](size_t bytes) { void* q = p; p += (bytes + 255) & ~(size_t)255; return q; };
    unsigned* egoA = (unsigned*)alloc((size_t)TOTAL * 2);      // bf16
    unsigned* egoB = (unsigned*)alloc((size_t)TOTAL * 2);      // bf16
    unsigned* hu   = (unsigned*)alloc((size_t)USER_NUM * EMB * 2);
    int*   ptrA  = (int*)alloc((size_t)(N_NODES + 1) * 4);
    int2*  packA = (int2*)alloc((size_t)adj_nnz * 8);
    int*   ptrS  = (int*)alloc((size_t)(USER_NUM + 1) * 4);
    int2*  packS = (int2*)alloc((size_t)s_nnz * 8);
    int*   auxRA = (int*)alloc((size_t)adj_nnz * 4);
    int*   auxCA = (int*)alloc((size_t)adj_nnz * 4);
    float* auxVA = (float*)alloc((size_t)adj_nnz * 4);
    int*   auxRS = (int*)alloc((size_t)s_nnz * 4);
    int*   auxCS = (int*)alloc((size_t)s_nnz * 4);
    float* auxVS = (float*)alloc((size_t)s_nnz * 4);
    int*   bcntA = (int*)alloc(64 * 4);
    int*   bcntS = (int*)alloc(64 * 4);
    int*   bbaseA= (int*)alloc(64 * 4);
    int*   bbaseS= (int*)alloc(64 * 4);
    int*   tailA = (int*)alloc(64 * 4);
    int*   tailS = (int*)alloc(64 * 4);

    const int BLK = 256;
    const int ew_grid = (TOTAL4 + BLK - 1) / BLK;
    const int nchA = (adj_nnz + BCHUNK - 1) / BCHUNK;
    const int nchS = (s_nnz + BCHUNK - 1) / BCHUNK;
    const int nccA = (adj_nnz + CCH - 1) / CCH;
    const int nccS = (s_nnz + CCH - 1) / CCH;

    // ---- CSR build ----
    zero_small<<<1, 64, 0, stream>>>(bcntA, bcntS);
    bucket_count<<<nccA + nccS, 256, 0, stream>>>(adj_rows, adj_nnz, nccA, bcntA,
                                                  s_rows, s_nnz, bcntS);
    scan_buckets<<<1, 64, 0, stream>>>(bcntA, bbaseA, tailA, ptrA,
                                       bcntS, bbaseS, tailS, ptrS);
    bucket_bin<<<nchA + nchS, 256, 0, stream>>>(
        adj_rows, adj_cols, adj_vals, adj_nnz, nchA, tailA, auxRA, auxCA, auxVA,
        s_rows, s_cols, s_vals, s_nnz, tailS, auxRS, auxCS, auxVS);
    bucket_fused<<<KA + KS, 1024, 0, stream>>>(
        auxRA, auxCA, auxVA, bbaseA, ptrA, packA,
        auxRS, auxCS, auxVS, bbaseS, ptrS, packS);

    // ---- init ----
    init_kernel<<<ew_grid, BLK, 0, stream>>>(user_emb, item_emb, egoA, acc);

    unsigned* ego  = egoA;
    unsigned* next = egoB;
    const int s_grid   = (USER_NUM + 3) / 4;
    const int adj_grid = (N_NODES + 3) / 4;

    for (int l = 0; l < N_LAYERS; ++l) {
        spmm_s<<<s_grid, BLK, 0, stream>>>(ptrS, packS, (const uint4*)ego, (uint4*)hu);
        spmm_adj<<<adj_grid, BLK, 0, stream>>>(ptrA, packA, (const uint4*)hu,
                                               (const uint4*)ego, (uint4*)next, acc,
                                               l == N_LAYERS - 1 ? 1 : 0);
        unsigned* t = ego; ego = next; next = t;
    }
}